// Round 1
// baseline (721.703 us; speedup 1.0000x reference)
//
#include <hip/hip_runtime.h>

#define D_FEAT 128

// One wave (64 lanes) per edge, grid-stride. Lane l handles features 2l, 2l+1.
// Accumulates h[src]*w into the h_N half of the output row (cols 128..255),
// so we only need n_nodes floats of workspace (deg).
__global__ void __launch_bounds__(256) edge_scatter_kernel(
    const float* __restrict__ h, const float* __restrict__ w,
    const int* __restrict__ src, const int* __restrict__ dst,
    float* __restrict__ out, float* __restrict__ deg, int n_edges)
{
    const int lane  = threadIdx.x & 63;
    const int wave  = (blockIdx.x * blockDim.x + threadIdx.x) >> 6;
    const int nwave = (gridDim.x * blockDim.x) >> 6;
    for (int e = wave; e < n_edges; e += nwave) {
        const int   s  = src[e];
        const int   d  = dst[e];
        const float we = w[e];
        const float2 hv = ((const float2*)(h + (size_t)s * D_FEAT))[lane];
        float* od = out + (size_t)d * (2 * D_FEAT) + D_FEAT + (lane << 1);
        atomicAdd(od,     hv.x * we);
        atomicAdd(od + 1, hv.y * we);
        if (lane == 0) atomicAdd(deg + d, 1.0f);
    }
}

// Per node: copy h into cols 0..127, scale cols 128..255 by 1/max(deg,1).
// 32 threads per node, one float4 from each half per thread.
__global__ void __launch_bounds__(256) finalize_kernel(
    const float* __restrict__ h, const float* __restrict__ deg,
    float* __restrict__ out, int n_nodes)
{
    int i = blockIdx.x * blockDim.x + threadIdx.x;
    const int total  = n_nodes * 32;
    const int stride = gridDim.x * blockDim.x;
    for (; i < total; i += stride) {
        const int n = i >> 5;
        const int q = i & 31;
        const float4 hv = ((const float4*)(h + (size_t)n * D_FEAT))[q];
        ((float4*)(out + (size_t)n * 2 * D_FEAT))[q] = hv;
        const float inv = 1.0f / fmaxf(deg[n], 1.0f);
        float4* ap = ((float4*)(out + (size_t)n * 2 * D_FEAT + D_FEAT)) + q;
        float4 a = *ap;
        a.x *= inv; a.y *= inv; a.z *= inv; a.w *= inv;
        *ap = a;
    }
}

extern "C" void kernel_launch(void* const* d_in, const int* in_sizes, int n_in,
                              void* d_out, int out_size, void* d_ws, size_t ws_size,
                              hipStream_t stream) {
    const float* h   = (const float*)d_in[0];
    const float* w   = (const float*)d_in[1];
    const int*   src = (const int*)d_in[2];
    const int*   dst = (const int*)d_in[3];
    float* out = (float*)d_out;
    float* deg = (float*)d_ws;

    const int n_edges = in_sizes[1];
    const int n_nodes = in_sizes[0] / D_FEAT;

    // Zero the accumulation targets every call (ws/out are poisoned, not re-zeroed).
    hipMemsetAsync(out, 0, (size_t)out_size * sizeof(float), stream);
    hipMemsetAsync(deg, 0, (size_t)n_nodes * sizeof(float), stream);

    // 2048 blocks x 256 threads = 8192 waves (full residency), grid-stride.
    edge_scatter_kernel<<<2048, 256, 0, stream>>>(h, w, src, dst, out, deg, n_edges);
    finalize_kernel<<<2048, 256, 0, stream>>>(h, deg, out, n_nodes);
}

// Round 2
// 146.143 us; speedup vs baseline: 4.9383x; 4.9383x over previous
//
#include <hip/hip_runtime.h>

#define D_FEAT 128
#define CAP 64   // per-node bin capacity; overflow handled exactly via list

// ---------------- fast path ----------------

__global__ void __launch_bounds__(256) fill_bins_kernel(
    const float* __restrict__ w, const int* __restrict__ src,
    const int* __restrict__ dst,
    int* __restrict__ count, int* __restrict__ ovf_count,
    int* __restrict__ ovf_list, int2* __restrict__ bins, int n_edges)
{
    int i = blockIdx.x * blockDim.x + threadIdx.x;
    const int stride = gridDim.x * blockDim.x;
    for (int e = i; e < n_edges; e += stride) {
        const int d = dst[e];
        const int pos = atomicAdd(&count[d], 1);
        if (pos < CAP) {
            bins[(size_t)d * CAP + pos] = make_int2(src[e], __float_as_int(w[e]));
        } else {
            const int o = atomicAdd(ovf_count, 1);
            ovf_list[o] = e;
        }
    }
}

// One wave per node: accumulate binned in-edges in registers, write full row.
__global__ void __launch_bounds__(256) gather_kernel(
    const float* __restrict__ h, const int* __restrict__ count,
    const int2* __restrict__ bins, float* __restrict__ out, int n_nodes)
{
    const int lane = threadIdx.x & 63;
    const int wave = (blockIdx.x * blockDim.x + threadIdx.x) >> 6;
    if (wave >= n_nodes) return;
    const int n   = wave;
    const int cnt = count[n];
    const int c   = cnt < CAP ? cnt : CAP;
    float2 acc = make_float2(0.0f, 0.0f);
    const int2* bp = bins + (size_t)n * CAP;
    for (int k = 0; k < c; ++k) {
        const int2  b  = bp[k];                       // wave-uniform broadcast
        const float ww = __int_as_float(b.y);
        const float2 hv = ((const float2*)(h + (size_t)b.x * D_FEAT))[lane];
        acc.x = fmaf(hv.x, ww, acc.x);
        acc.y = fmaf(hv.y, ww, acc.y);
    }
    const float inv = 1.0f / fmaxf((float)cnt, 1.0f);
    const float2 hself = ((const float2*)(h + (size_t)n * D_FEAT))[lane];
    float2* orow = (float2*)(out + (size_t)n * 2 * D_FEAT);
    orow[lane]      = hself;                          // cols 0..127
    orow[lane + 64] = make_float2(acc.x * inv, acc.y * inv); // cols 128..255
}

// Exact fixup for edges that exceeded CAP (expected: none). Runs AFTER gather.
__global__ void __launch_bounds__(256) overflow_kernel(
    const float* __restrict__ h, const float* __restrict__ w,
    const int* __restrict__ src, const int* __restrict__ dst,
    const int* __restrict__ count, const int* __restrict__ ovf_count,
    const int* __restrict__ ovf_list, float* __restrict__ out)
{
    const int novf = *ovf_count;
    if (novf == 0) return;
    const int lane  = threadIdx.x & 63;
    const int wave  = (blockIdx.x * blockDim.x + threadIdx.x) >> 6;
    const int nwave = (gridDim.x * blockDim.x) >> 6;
    for (int idx = wave; idx < novf; idx += nwave) {
        const int e = ovf_list[idx];
        const int s = src[e];
        const int d = dst[e];
        const float scale = w[e] / fmaxf((float)count[d], 1.0f);
        const float2 hv = ((const float2*)(h + (size_t)s * D_FEAT))[lane];
        float* od = out + (size_t)d * 2 * D_FEAT + D_FEAT + (lane << 1);
        atomicAdd(od,     hv.x * scale);
        atomicAdd(od + 1, hv.y * scale);
    }
}

// ---------------- fallback path (round-1 atomic version) ----------------

__global__ void __launch_bounds__(256) edge_scatter_kernel(
    const float* __restrict__ h, const float* __restrict__ w,
    const int* __restrict__ src, const int* __restrict__ dst,
    float* __restrict__ out, float* __restrict__ deg, int n_edges)
{
    const int lane  = threadIdx.x & 63;
    const int wave  = (blockIdx.x * blockDim.x + threadIdx.x) >> 6;
    const int nwave = (gridDim.x * blockDim.x) >> 6;
    for (int e = wave; e < n_edges; e += nwave) {
        const int   s  = src[e];
        const int   d  = dst[e];
        const float we = w[e];
        const float2 hv = ((const float2*)(h + (size_t)s * D_FEAT))[lane];
        float* od = out + (size_t)d * (2 * D_FEAT) + D_FEAT + (lane << 1);
        atomicAdd(od,     hv.x * we);
        atomicAdd(od + 1, hv.y * we);
        if (lane == 0) atomicAdd(deg + d, 1.0f);
    }
}

__global__ void __launch_bounds__(256) finalize_kernel(
    const float* __restrict__ h, const float* __restrict__ deg,
    float* __restrict__ out, int n_nodes)
{
    int i = blockIdx.x * blockDim.x + threadIdx.x;
    const int total  = n_nodes * 32;
    const int stride = gridDim.x * blockDim.x;
    for (; i < total; i += stride) {
        const int n = i >> 5;
        const int q = i & 31;
        const float4 hv = ((const float4*)(h + (size_t)n * D_FEAT))[q];
        ((float4*)(out + (size_t)n * 2 * D_FEAT))[q] = hv;
        const float inv = 1.0f / fmaxf(deg[n], 1.0f);
        float4* ap = ((float4*)(out + (size_t)n * 2 * D_FEAT + D_FEAT)) + q;
        float4 a = *ap;
        a.x *= inv; a.y *= inv; a.z *= inv; a.w *= inv;
        *ap = a;
    }
}

// ---------------- launch ----------------

extern "C" void kernel_launch(void* const* d_in, const int* in_sizes, int n_in,
                              void* d_out, int out_size, void* d_ws, size_t ws_size,
                              hipStream_t stream) {
    const float* h   = (const float*)d_in[0];
    const float* w   = (const float*)d_in[1];
    const int*   src = (const int*)d_in[2];
    const int*   dst = (const int*)d_in[3];
    float* out = (float*)d_out;

    const int n_edges = in_sizes[1];
    const int n_nodes = in_sizes[0] / D_FEAT;

    // ws layout: count[n_nodes] | ovf_count[1] (+pad to 4 ints) | bins[n_nodes*CAP] int2 | ovf_list[n_edges]
    const size_t count_bytes = (size_t)(n_nodes + 4) * sizeof(int);
    const size_t bins_bytes  = (size_t)n_nodes * CAP * sizeof(int2);
    const size_t ovf_bytes   = (size_t)n_edges * sizeof(int);
    const size_t need        = count_bytes + bins_bytes + ovf_bytes;

    if (ws_size >= need) {
        int*  count     = (int*)d_ws;
        int*  ovf_count = count + n_nodes;
        int2* bins      = (int2*)((char*)d_ws + count_bytes);
        int*  ovf_list  = (int*)((char*)d_ws + count_bytes + bins_bytes);

        hipMemsetAsync(count, 0, count_bytes, stream);
        fill_bins_kernel<<<2048, 256, 0, stream>>>(w, src, dst, count, ovf_count,
                                                   ovf_list, bins, n_edges);
        gather_kernel<<<(n_nodes + 3) / 4, 256, 0, stream>>>(h, count, bins, out, n_nodes);
        overflow_kernel<<<256, 256, 0, stream>>>(h, w, src, dst, count, ovf_count,
                                                 ovf_list, out);
    } else {
        // Safety fallback: atomic scatter (correct, slower).
        float* deg = (float*)d_ws;
        hipMemsetAsync(out, 0, (size_t)out_size * sizeof(float), stream);
        hipMemsetAsync(deg, 0, (size_t)n_nodes * sizeof(float), stream);
        edge_scatter_kernel<<<2048, 256, 0, stream>>>(h, w, src, dst, out, deg, n_edges);
        finalize_kernel<<<2048, 256, 0, stream>>>(h, deg, out, n_nodes);
    }
}

// Round 3
// 120.386 us; speedup vs baseline: 5.9949x; 1.2140x over previous
//
#include <hip/hip_runtime.h>

#define D_FEAT 128
#define CAP 64   // per-node bin capacity; overflow handled exactly via list

// ---------------- fast path ----------------

__global__ void __launch_bounds__(256) fill_bins_kernel(
    const float* __restrict__ w, const int* __restrict__ src,
    const int* __restrict__ dst,
    int* __restrict__ count, int* __restrict__ ovf_count,
    int* __restrict__ ovf_list, int2* __restrict__ bins, int n_edges)
{
    int i = blockIdx.x * blockDim.x + threadIdx.x;
    const int stride = gridDim.x * blockDim.x;
    for (int e = i; e < n_edges; e += stride) {
        const int d = dst[e];
        const int pos = atomicAdd(&count[d], 1);
        if (pos < CAP) {
            bins[(size_t)d * CAP + pos] = make_int2(src[e], __float_as_int(w[e]));
        } else {
            const int o = atomicAdd(ovf_count, 1);
            ovf_list[o] = e;
        }
    }
}

// One wave per node. 8-wide unrolled gather: batch bin reads (int4 pairs),
// issue 8 independent h-row gathers to hide L2/L3 latency, then fmaf.
__global__ void __launch_bounds__(256) gather_kernel(
    const float* __restrict__ h, const int* __restrict__ count,
    const int2* __restrict__ bins, float* __restrict__ out, int n_nodes)
{
    const int lane = threadIdx.x & 63;
    const int wave = (blockIdx.x * blockDim.x + threadIdx.x) >> 6;
    if (wave >= n_nodes) return;
    const int n   = wave;
    const int cnt = count[n];
    const int c   = cnt < CAP ? cnt : CAP;
    float2 acc = make_float2(0.0f, 0.0f);
    const int2* bp  = bins + (size_t)n * CAP;
    const int4* bp4 = (const int4*)bp;

    int k = 0;
    for (; k + 8 <= c; k += 8) {
        const int kk = k >> 1;
        const int4 p0 = bp4[kk + 0];
        const int4 p1 = bp4[kk + 1];
        const int4 p2 = bp4[kk + 2];
        const int4 p3 = bp4[kk + 3];
        const float2 h0 = ((const float2*)(h + (size_t)p0.x * D_FEAT))[lane];
        const float2 h1 = ((const float2*)(h + (size_t)p0.z * D_FEAT))[lane];
        const float2 h2 = ((const float2*)(h + (size_t)p1.x * D_FEAT))[lane];
        const float2 h3 = ((const float2*)(h + (size_t)p1.z * D_FEAT))[lane];
        const float2 h4 = ((const float2*)(h + (size_t)p2.x * D_FEAT))[lane];
        const float2 h5 = ((const float2*)(h + (size_t)p2.z * D_FEAT))[lane];
        const float2 h6 = ((const float2*)(h + (size_t)p3.x * D_FEAT))[lane];
        const float2 h7 = ((const float2*)(h + (size_t)p3.z * D_FEAT))[lane];
        const float w0 = __int_as_float(p0.y), w1 = __int_as_float(p0.w);
        const float w2 = __int_as_float(p1.y), w3 = __int_as_float(p1.w);
        const float w4 = __int_as_float(p2.y), w5 = __int_as_float(p2.w);
        const float w6 = __int_as_float(p3.y), w7 = __int_as_float(p3.w);
        acc.x = fmaf(h0.x, w0, acc.x); acc.y = fmaf(h0.y, w0, acc.y);
        acc.x = fmaf(h1.x, w1, acc.x); acc.y = fmaf(h1.y, w1, acc.y);
        acc.x = fmaf(h2.x, w2, acc.x); acc.y = fmaf(h2.y, w2, acc.y);
        acc.x = fmaf(h3.x, w3, acc.x); acc.y = fmaf(h3.y, w3, acc.y);
        acc.x = fmaf(h4.x, w4, acc.x); acc.y = fmaf(h4.y, w4, acc.y);
        acc.x = fmaf(h5.x, w5, acc.x); acc.y = fmaf(h5.y, w5, acc.y);
        acc.x = fmaf(h6.x, w6, acc.x); acc.y = fmaf(h6.y, w6, acc.y);
        acc.x = fmaf(h7.x, w7, acc.x); acc.y = fmaf(h7.y, w7, acc.y);
    }
    for (; k < c; ++k) {
        const int2  b  = bp[k];
        const float ww = __int_as_float(b.y);
        const float2 hv = ((const float2*)(h + (size_t)b.x * D_FEAT))[lane];
        acc.x = fmaf(hv.x, ww, acc.x);
        acc.y = fmaf(hv.y, ww, acc.y);
    }
    const float inv = 1.0f / fmaxf((float)cnt, 1.0f);
    const float2 hself = ((const float2*)(h + (size_t)n * D_FEAT))[lane];
    float2* orow = (float2*)(out + (size_t)n * 2 * D_FEAT);
    orow[lane]      = hself;                                  // cols 0..127
    orow[lane + 64] = make_float2(acc.x * inv, acc.y * inv);  // cols 128..255
}

// Exact fixup for edges that exceeded CAP (expected: none). Runs AFTER gather.
__global__ void __launch_bounds__(256) overflow_kernel(
    const float* __restrict__ h, const float* __restrict__ w,
    const int* __restrict__ src, const int* __restrict__ dst,
    const int* __restrict__ count, const int* __restrict__ ovf_count,
    const int* __restrict__ ovf_list, float* __restrict__ out)
{
    const int novf = *ovf_count;
    if (novf == 0) return;
    const int lane  = threadIdx.x & 63;
    const int wave  = (blockIdx.x * blockDim.x + threadIdx.x) >> 6;
    const int nwave = (gridDim.x * blockDim.x) >> 6;
    for (int idx = wave; idx < novf; idx += nwave) {
        const int e = ovf_list[idx];
        const int s = src[e];
        const int d = dst[e];
        const float scale = w[e] / fmaxf((float)count[d], 1.0f);
        const float2 hv = ((const float2*)(h + (size_t)s * D_FEAT))[lane];
        float* od = out + (size_t)d * 2 * D_FEAT + D_FEAT + (lane << 1);
        atomicAdd(od,     hv.x * scale);
        atomicAdd(od + 1, hv.y * scale);
    }
}

// ---------------- fallback path (atomic version) ----------------

__global__ void __launch_bounds__(256) edge_scatter_kernel(
    const float* __restrict__ h, const float* __restrict__ w,
    const int* __restrict__ src, const int* __restrict__ dst,
    float* __restrict__ out, float* __restrict__ deg, int n_edges)
{
    const int lane  = threadIdx.x & 63;
    const int wave  = (blockIdx.x * blockDim.x + threadIdx.x) >> 6;
    const int nwave = (gridDim.x * blockDim.x) >> 6;
    for (int e = wave; e < n_edges; e += nwave) {
        const int   s  = src[e];
        const int   d  = dst[e];
        const float we = w[e];
        const float2 hv = ((const float2*)(h + (size_t)s * D_FEAT))[lane];
        float* od = out + (size_t)d * (2 * D_FEAT) + D_FEAT + (lane << 1);
        atomicAdd(od,     hv.x * we);
        atomicAdd(od + 1, hv.y * we);
        if (lane == 0) atomicAdd(deg + d, 1.0f);
    }
}

__global__ void __launch_bounds__(256) finalize_kernel(
    const float* __restrict__ h, const float* __restrict__ deg,
    float* __restrict__ out, int n_nodes)
{
    int i = blockIdx.x * blockDim.x + threadIdx.x;
    const int total  = n_nodes * 32;
    const int stride = gridDim.x * blockDim.x;
    for (; i < total; i += stride) {
        const int n = i >> 5;
        const int q = i & 31;
        const float4 hv = ((const float4*)(h + (size_t)n * D_FEAT))[q];
        ((float4*)(out + (size_t)n * 2 * D_FEAT))[q] = hv;
        const float inv = 1.0f / fmaxf(deg[n], 1.0f);
        float4* ap = ((float4*)(out + (size_t)n * 2 * D_FEAT + D_FEAT)) + q;
        float4 a = *ap;
        a.x *= inv; a.y *= inv; a.z *= inv; a.w *= inv;
        *ap = a;
    }
}

// ---------------- launch ----------------

extern "C" void kernel_launch(void* const* d_in, const int* in_sizes, int n_in,
                              void* d_out, int out_size, void* d_ws, size_t ws_size,
                              hipStream_t stream) {
    const float* h   = (const float*)d_in[0];
    const float* w   = (const float*)d_in[1];
    const int*   src = (const int*)d_in[2];
    const int*   dst = (const int*)d_in[3];
    float* out = (float*)d_out;

    const int n_edges = in_sizes[1];
    const int n_nodes = in_sizes[0] / D_FEAT;

    // ws layout: count[n_nodes] | ovf_count[1] (+pad to 4 ints) | bins[n_nodes*CAP] int2 | ovf_list[n_edges]
    const size_t count_bytes = (size_t)(n_nodes + 4) * sizeof(int);
    const size_t bins_bytes  = (size_t)n_nodes * CAP * sizeof(int2);
    const size_t ovf_bytes   = (size_t)n_edges * sizeof(int);
    const size_t need        = count_bytes + bins_bytes + ovf_bytes;

    if (ws_size >= need) {
        int*  count     = (int*)d_ws;
        int*  ovf_count = count + n_nodes;
        int2* bins      = (int2*)((char*)d_ws + count_bytes);
        int*  ovf_list  = (int*)((char*)d_ws + count_bytes + bins_bytes);

        hipMemsetAsync(count, 0, count_bytes, stream);
        fill_bins_kernel<<<2048, 256, 0, stream>>>(w, src, dst, count, ovf_count,
                                                   ovf_list, bins, n_edges);
        gather_kernel<<<(n_nodes + 3) / 4, 256, 0, stream>>>(h, count, bins, out, n_nodes);
        overflow_kernel<<<64, 256, 0, stream>>>(h, w, src, dst, count, ovf_count,
                                                ovf_list, out);
    } else {
        // Safety fallback: atomic scatter (correct, slower).
        float* deg = (float*)d_ws;
        hipMemsetAsync(out, 0, (size_t)out_size * sizeof(float), stream);
        hipMemsetAsync(deg, 0, (size_t)n_nodes * sizeof(float), stream);
        edge_scatter_kernel<<<2048, 256, 0, stream>>>(h, w, src, dst, out, deg, n_edges);
        finalize_kernel<<<2048, 256, 0, stream>>>(h, deg, out, n_nodes);
    }
}